// Round 19
// baseline (2480.959 us; speedup 1.0000x reference)
//
#include <hip/hip_runtime.h>
#include <cmath>

// ---------------------------------------------------------------------------
// ACT classifier (B=65536, D=512, H=256, C=100, T=10).
// Round 19 = round 18 (= r14, best verified 1986-1999us) + ONE bit-identical
// relocation: t=0's k_gru (which skips its GEMM; only re-reads xpt and runs
// gates+dumps) is folded into k_xproj's epilogue, which already holds the
// same xpt values in registers. Saves one dispatch + a 201MB xpt re-read;
// adds the h_seq/h16[t=0] writes to k_xproj (LDS aliased, two 64-row tile
// passes). Gate math identity: fmaf(x*2^16, 2^-16, b) == round(x+b) ==
// x + b, so h0/halt values match k_gru's t=0 path; staging/dump layouts
// transplanted verbatim. k_gru untouched; its loop runs t=1..9.
// Canary: absmax must stay exactly 0.0078125.
// ---------------------------------------------------------------------------

namespace {
constexpr int B = 65536, D = 512, H = 256, C = 100, T = 10;

// output layout (flat float elements, reference return order)
constexpr long OUT_LOGITS = 0;
constexpr long OUT_PONDER = (long)B * C;
constexpr long OUT_NUP    = OUT_PONDER + 1;
constexpr long OUT_HSEQ   = OUT_NUP + B;
constexpr long OUT_HALT   = OUT_HSEQ + (long)B * T * H;
constexpr long OUT_LSEQ   = OUT_HALT + (long)B * T;

// weight plane sizes (elements)
constexpr long NIH  = 768L * D;   // 393216
constexpr long NHH  = 768L * H;   // 196608
constexpr long NAUG = 112L * H;   // 28672

// workspace layout (float units)
constexpr long WS_XP   = 0;                          // xpt [B*768] f32 (tiled)
constexpr long WS_W16  = WS_XP + (long)B * 768;      // f16 planes (2x each W)
constexpr long W_HALV  = 2 * (NIH + NHH + NAUG);
constexpr long WS_HL   = WS_W16 + (W_HALV + 1) / 2;  // step_w [B][T]
constexpr long WS_HP4  = WS_HL + (long)B * T;        // halt partials [T][4][B]
constexpr long WS_NUPB = WS_HP4 + 4L * B * T;
constexpr long WS_REMB = WS_NUPB + B;
constexpr long WS_H16  = WS_REMB + B;                // h16 planes, per t
// h16: [t][tile 1024][kc 8][plane 2][r 64][kk 32] halves
constexpr long H16_PER_T = 1024L * 32768;            // 33,554,432 halves / t

constexpr float SC  = 256.f;           // operand pre-scale 2^8
constexpr float ISC = 1.f / 256.f;     // single-operand scale-back 2^-8
constexpr float SB  = 1.f / 65536.f;   // product scale-back 2^-16 (exact)
} // namespace

typedef __attribute__((ext_vector_type(8))) _Float16 h8;
typedef __attribute__((ext_vector_type(4))) _Float16 h4;
typedef __attribute__((ext_vector_type(4))) float f4;

#define MFMA16(A, Bo, Cc) __builtin_amdgcn_mfma_f32_16x16x32_f16(A, Bo, Cc, 0, 0, 0)
// 3-product 2-split accumulate, smallest first
#define PROD3(a, Ah, Al, Bh, Bl)                                               \
  a = MFMA16(Al, Bh, a);                                                       \
  a = MFMA16(Ah, Bl, a);                                                       \
  a = MFMA16(Ah, Bh, a);

__device__ __forceinline__ float sigmoidf_(float x) {
  if (x >= 0.f) { return 1.f / (1.f + expf(-x)); }
  float e = expf(x);
  return e / (1.f + e);
}

// async global->LDS DMA, 16 B per lane; lds base wave-uniform, fills
// base + lane*16 linearly; global src is per-lane.
__device__ __forceinline__ void gload_lds16(const _Float16* g, _Float16* l) {
  __builtin_amdgcn_global_load_lds(
      (const __attribute__((address_space(1))) unsigned int*)g,
      (__attribute__((address_space(3))) unsigned int*)l, 16, 0, 0);
}

// ---------------------------------------------------------------------------
// split weights (pre-scaled by 2^8) into f16 hi/lo planes
__global__ void k_prep(const float* __restrict__ wih_s, const float* __restrict__ whh_s,
                       const float* __restrict__ wro, const float* __restrict__ whalt,
                       _Float16* __restrict__ wr) {
  long idx = (long)blockIdx.x * 256 + threadIdx.x;
  if (idx < NIH) {
    float xs = wih_s[idx] * SC;
    _Float16 h = (_Float16)xs;
    _Float16 l = (_Float16)(xs - (float)h);
    wr[idx] = h; wr[NIH + idx] = l;
  }
  if (idx < NHH) {
    float xs = whh_s[idx] * SC;
    _Float16 h = (_Float16)xs;
    _Float16 l = (_Float16)(xs - (float)h);
    long b = 2 * NIH;
    wr[b + idx] = h; wr[b + NHH + idx] = l;
  }
  if (idx < NAUG) {
    int row = (int)(idx >> 8), k = (int)(idx & 255);
    float x = (row < C) ? wro[row * 256 + k] : ((row == C) ? whalt[k] : 0.f);
    float xs = x * SC;
    _Float16 h = (_Float16)xs;
    _Float16 l = (_Float16)(xs - (float)h);
    long b = 2 * (NIH + NHH);
    wr[b + idx] = h; wr[b + NAUG + idx] = l;
  }
}

// stage 16 fp32 elems (scaled) as f16 hi/lo into LDS at row*40+kk0
__device__ __forceinline__ void stageA16(const float* __restrict__ src,
                                         _Float16* As0, _Float16* As1,
                                         int o) {
#pragma unroll
  for (int i = 0; i < 4; ++i) {
    float4 v = ((const float4*)src)[i];
    float vv[4] = {v.x, v.y, v.z, v.w};
    h4 hh, ll;
#pragma unroll
    for (int c = 0; c < 4; ++c) {
      float sv = vv[c] * SC;
      _Float16 h = (_Float16)sv;
      hh[c] = h;
      ll[c] = (_Float16)(sv - (float)h);
    }
    *(h4*)&As0[o + i * 4] = hh;
    *(h4*)&As1[o + i * 4] = ll;
  }
}

// ---------------------------------------------------------------------------
// xpt = x @ W_ih^T + b_ih, stored TILED in MFMA C-fragment order; ALSO
// computes the t=0 GRU output (h_seq[0], h16[0], halt partials) from the
// same register values. Grid 2048 (XCD-swizzled: 512 row-tiles x 4 strips).
__global__ __launch_bounds__(256, 3) void k_xproj(
    const float* __restrict__ x, const _Float16* __restrict__ wih,
    const float* __restrict__ b_ih, const float* __restrict__ b_hh,
    const float* __restrict__ w_halt, float* __restrict__ xpt,
    float* __restrict__ out, _Float16* __restrict__ h16,
    float* __restrict__ hp4) {
  __shared__ __align__(16) char uSmem[45056];   // As0|As1|Bs0|Bs1  /  hseqS|h16S
  _Float16* As0 = (_Float16*)uSmem;             // [128*40] 10240 B
  _Float16* As1 = (_Float16*)(uSmem + 10240);   // [128*40] 10240 B
  _Float16* Bs0 = (_Float16*)(uSmem + 20480);   // [192*32] 12288 B
  _Float16* Bs1 = (_Float16*)(uSmem + 32768);   // [192*32] 12288 B
  float*    hseqS = (float*)uSmem;              // [64][64] 16 KB (per pass)
  _Float16* h16S  = (_Float16*)(uSmem + 16384); // [4][64][32] 16 KB (per pass)
  __shared__ float lds_hp[128][4];
  const int tid = threadIdx.x;
  const int w = tid >> 6, l = tid & 63;
  const int lr = l & 15, lq = l >> 4;
  const int bid = blockIdx.x;
  const int gid = (bid & 7) * 256 + (bid >> 3);   // XCD-contiguous
  const int c0 = (gid & 3) * 64;
  const int rb = (gid >> 2) * 128;

  f4 acc[8][3];
#pragma unroll
  for (int i = 0; i < 8; ++i)
#pragma unroll
    for (int g = 0; g < 3; ++g) acc[i][g] = (f4)0.f;

  for (int kc = 0; kc < 16; ++kc) {
    const int k0 = kc * 32;
    __syncthreads();
    {  // stage A (x rows, scaled split)
      const int row = tid >> 1, kk0 = (tid & 1) * 16;
      stageA16(x + (long)(rb + row) * D + k0 + kk0, As0, As1, row * 40 + kk0);
    }
    // stage B via async DMA: 2 planes x 12 KB, 6 x 1KB chunks per wave
#pragma unroll
    for (int j = 0; j < 6; ++j) {
      int chunk = w * 6 + j;           // 0..23
      int plane = chunk / 12;
      int rem = chunk - plane * 12;
      int scol = rem * 16 + (l >> 2);
      int kq = l & 3;
      int gcol = (scol >> 6) * 256 + c0 + (scol & 63);
      gload_lds16(wih + (long)plane * NIH + (long)gcol * D + k0 + kq * 8,
                  (plane ? Bs1 : Bs0) + rem * 512);
    }
    __syncthreads();
    h8 Bh[3], Bl[3];
#pragma unroll
    for (int g = 0; g < 3; ++g) {
      Bh[g] = *(const h8*)&Bs0[(g * 64 + w * 16 + lr) * 32 + lq * 8];
      Bl[g] = *(const h8*)&Bs1[(g * 64 + w * 16 + lr) * 32 + lq * 8];
    }
#pragma unroll
    for (int i = 0; i < 8; ++i) {
      h8 Ah = *(const h8*)&As0[(i * 16 + lr) * 40 + lq * 8];
      h8 Al = *(const h8*)&As1[(i * 16 + lr) * 40 + lq * 8];
#pragma unroll
      for (int g = 0; g < 3; ++g) { PROD3(acc[i][g], Ah, Al, Bh[g], Bl[g]); }
    }
  }
  const int ch = c0 + w * 16 + lr;
  const int strip = gid & 3;
  float bi[3] = {b_ih[ch], b_ih[256 + ch], b_ih[512 + ch]};
  const long xoff = (long)(lq * 256 + w * 64 + lr * 4);
#pragma unroll
  for (int i = 0; i < 8; ++i) {
    const long t4s = (long)((gid >> 2) * 2 + (i >> 2)) * 4 + strip;
#pragma unroll
    for (int g = 0; g < 3; ++g) {
      float4 v = make_float4(fmaf(acc[i][g][0], SB, bi[g]),
                             fmaf(acc[i][g][1], SB, bi[g]),
                             fmaf(acc[i][g][2], SB, bi[g]),
                             fmaf(acc[i][g][3], SB, bi[g]));
      *(float4*)&xpt[((t4s * 3 + g) * 4 + (i & 3)) * 1024 + xoff] = v;
    }
  }

  // ---- t=0 GRU fold: gates on the same register values; two 64-row passes.
  // Identity with k_gru t=0: fmaf(x*2^16, 2^-16, b) == x + b (single
  // rounding); ho = 0. Staging/dump layouts transplanted from k_gru.
  const float bhr = b_hh[ch], bhz = b_hh[256 + ch], bhn = b_hh[512 + ch];
  const float whv = w_halt[ch];
  const int kcl = w >> 1;                 // local kc within strip (0/1)
  const int kk = (w & 1) * 16 + lr;       // ch & 31
  for (int tl = 0; tl < 2; ++tl) {
    __syncthreads();                      // As/Bs reads done / prev pass done
#pragma unroll
    for (int ii = 0; ii < 4; ++ii) {
      const int i = tl * 4 + ii;
#pragma unroll
      for (int reg = 0; reg < 4; ++reg) {
        const int rloc = ii * 16 + lq * 4 + reg;
        float xrv = fmaf(acc[i][0][reg], SB, bi[0]);
        float xzv = fmaf(acc[i][1][reg], SB, bi[1]);
        float xnv = fmaf(acc[i][2][reg], SB, bi[2]);
        float rr = sigmoidf_(xrv + bhr);
        float zz = sigmoidf_(xzv + bhz);
        float nn = tanhf(xnv + rr * bhn);
        float hv = (1.f - zz) * nn + zz * 0.f;
        hseqS[rloc * 64 + w * 16 + lr] = hv;
        float sv = hv * SC;
        _Float16 hi = (_Float16)sv;
        _Float16 lo = (_Float16)(sv - (float)hi);
        h16S[(kcl * 2 + 0) * 2048 + rloc * 32 + kk] = hi;
        h16S[(kcl * 2 + 1) * 2048 + rloc * 32 + kk] = lo;
        float p = hv * whv;
#pragma unroll
        for (int m = 1; m < 16; m <<= 1) p += __shfl_xor(p, m, 64);
        if (lr == 0) lds_hp[tl * 64 + rloc][w] = p;
      }
    }
    __syncthreads();
    // dump h_seq rows of this tile (t=0), 256B contiguous segments
#pragma unroll
    for (int k = 0; k < 4; ++k) {
      int cid = k * 256 + tid;            // 0..1023 16B-chunks
      int row = cid >> 4, ch16 = cid & 15;
      *(float4*)&out[OUT_HSEQ + (long)(rb + tl * 64 + row) * (T * H) + c0 + ch16 * 4] =
          *(const float4*)&hseqS[row * 64 + ch16 * 4];
    }
    // dump h16[t=0] for tile (rb>>6)+tl: one contiguous 16KB block
    {
      _Float16* dst = h16 + ((long)(rb >> 6) + tl) * 32768 + (long)(2 * strip) * 4096;
#pragma unroll
      for (int k = 0; k < 4; ++k) {
        int cid = k * 256 + tid;          // 16B chunks of 16KB
        *(float4*)&dst[cid * 8] = *(const float4*)&h16S[cid * 8];
      }
    }
  }
  __syncthreads();
  if (tid < 128)
    hp4[(long)strip * B + rb + tid] =
        (lds_hp[tid][0] + lds_hp[tid][1]) + (lds_hp[tid][2] + lds_hp[tid][3]);
}

// ---------------------------------------------------------------------------
// One GRU step, 64-row tiles (round 12 structure; runs t=1..9). Epilogue
// stores staged in LDS (aliasing As/Bs) and dumped as contiguous segments.
__global__ __launch_bounds__(256, 4) void k_gru(
    const _Float16* __restrict__ whh, const float* __restrict__ xpt,
    const float* __restrict__ b_hh, const float* __restrict__ w_halt,
    float* __restrict__ out, _Float16* __restrict__ h16,
    float* __restrict__ hp4, int t) {
  __shared__ __align__(16) char uSmem[32768];      // As(8K)+Bs(24K) | hseqS(16K)+h16S(16K)
  _Float16* As0 = (_Float16*)uSmem;                // [64*32] plane 0
  _Float16* As1 = (_Float16*)(uSmem + 4096);       // [64*32] plane 1
  _Float16* Bs0 = (_Float16*)(uSmem + 8192);       // [192*32] plane 0
  _Float16* Bs1 = (_Float16*)(uSmem + 20480);      // [192*32] plane 1
  float*    hseqS = (float*)uSmem;                 // [64][64] post-loop
  _Float16* h16S  = (_Float16*)(uSmem + 16384);    // [4][64][32] post-loop
  __shared__ float lds_hp[64][4];
  const int tid = threadIdx.x;
  const int w = tid >> 6, l = tid & 63;
  const int lr = l & 15, lq = l >> 4;
  const int bid = blockIdx.x;
  const int gid = (bid & 7) * 512 + (bid >> 3);   // XCD-contiguous
  const int strip = gid & 3;
  const int c0 = strip * 64;
  const int rb = (gid >> 2) * 64;
  const long tilebase = (long)(rb >> 6) * 32768;  // 8 kc * 2 planes * 2048
  const int ch = c0 + w * 16 + lr;
  const int kc_h = ch >> 5;                       // wave-uniform

  f4 acc[4][3];
  float ho[4][4];
  float xnv[4][4];
  // init: coalesced float4 fragment loads; xr/xz folded into acc (exact
  // *2^16), xn prefetched.
  const long t4s = (long)(gid >> 2) * 4 + strip;
  const long xoff = (long)(lq * 256 + w * 64 + lr * 4);
#pragma unroll
  for (int i = 0; i < 4; ++i) {
    float4 vr = *(const float4*)&xpt[((t4s * 3 + 0) * 4 + i) * 1024 + xoff];
    float4 vz = *(const float4*)&xpt[((t4s * 3 + 1) * 4 + i) * 1024 + xoff];
    float4 vn = *(const float4*)&xpt[((t4s * 3 + 2) * 4 + i) * 1024 + xoff];
    acc[i][0][0] = vr.x * 65536.f; acc[i][0][1] = vr.y * 65536.f;
    acc[i][0][2] = vr.z * 65536.f; acc[i][0][3] = vr.w * 65536.f;
    acc[i][1][0] = vz.x * 65536.f; acc[i][1][1] = vz.y * 65536.f;
    acc[i][1][2] = vz.z * 65536.f; acc[i][1][3] = vz.w * 65536.f;
    xnv[i][0] = vn.x; xnv[i][1] = vn.y; xnv[i][2] = vn.z; xnv[i][3] = vn.w;
    acc[i][2] = (f4)0.f;
#pragma unroll
    for (int reg = 0; reg < 4; ++reg) ho[i][reg] = 0.f;
  }

  if (t > 0) {
    const _Float16* h16r = h16 + (long)(t - 1) * H16_PER_T + tilebase;
    for (int kc = 0; kc < 8; ++kc) {
      const int k0 = kc * 32;
      __syncthreads();
      // stage A via DMA: 2 planes x 4KB = 8 chunks of 1KB; 2 per wave
#pragma unroll
      for (int j = 0; j < 2; ++j) {
        int c = w * 2 + j;          // 0..7
        int plane = c >> 2;
        int cc = c & 3;
        gload_lds16(h16r + (long)kc * 4096 + plane * 2048 + cc * 512 + l * 8,
                    (plane ? As1 : As0) + cc * 512);
      }
      // stage B via DMA: 24 x 1KB chunks, 6 per wave
#pragma unroll
      for (int j = 0; j < 6; ++j) {
        int chunk = w * 6 + j;
        int plane = chunk / 12;
        int rem = chunk - plane * 12;
        int scol = rem * 16 + (l >> 2);
        int kq = l & 3;
        int gcol = (scol >> 6) * 256 + c0 + (scol & 63);
        gload_lds16(whh + (long)plane * NHH + (long)gcol * H + k0 + kq * 8,
                    (plane ? Bs1 : Bs0) + rem * 512);
      }
      __syncthreads();
      h8 Bh[3], Bl[3];
#pragma unroll
      for (int g = 0; g < 3; ++g) {
        Bh[g] = *(const h8*)&Bs0[(g * 64 + w * 16 + lr) * 32 + lq * 8];
        Bl[g] = *(const h8*)&Bs1[(g * 64 + w * 16 + lr) * 32 + lq * 8];
      }
#pragma unroll
      for (int i = 0; i < 4; ++i) {
        h8 Ah = *(const h8*)&As0[(i * 16 + lr) * 32 + lq * 8];
        h8 Al = *(const h8*)&As1[(i * 16 + lr) * 32 + lq * 8];
#pragma unroll
        for (int g = 0; g < 3; ++g) { PROD3(acc[i][g], Ah, Al, Bh[g], Bl[g]); }
      }
      // capture ho = h_{t-1}[row, ch] from this kc's As tile: (hi+lo)/SC
      if (kc == kc_h) {
#pragma unroll
        for (int i = 0; i < 4; ++i)
#pragma unroll
          for (int reg = 0; reg < 4; ++reg) {
            int rloc = i * 16 + lq * 4 + reg;
            ho[i][reg] = ((float)As0[rloc * 32 + (ch & 31)] +
                          (float)As1[rloc * 32 + (ch & 31)]) * ISC;
          }
      }
    }
  }

  // epilogue: gates + h_new in registers (no global loads, no stores yet)
  const float bhr = b_hh[ch], bhz = b_hh[256 + ch], bhn = b_hh[512 + ch];
  const float whv = w_halt[ch];
  float hvv[4][4];
#pragma unroll
  for (int i = 0; i < 4; ++i)
#pragma unroll
    for (int reg = 0; reg < 4; ++reg) {
      float rr = sigmoidf_(fmaf(acc[i][0][reg], SB, bhr));
      float zz = sigmoidf_(fmaf(acc[i][1][reg], SB, bhz));
      float nn = tanhf(xnv[i][reg] + rr * fmaf(acc[i][2][reg], SB, bhn));
      hvv[i][reg] = (1.f - zz) * nn + zz * ho[i][reg];
    }

  __syncthreads();   // As/Bs consumption fully done; alias region reusable

  // stage h_seq + h16 planes into LDS; halt partial via shuffle
  const int kcl = w >> 1;                 // local kc within strip (0/1)
  const int kk = (w & 1) * 16 + lr;       // ch & 31
#pragma unroll
  for (int i = 0; i < 4; ++i)
#pragma unroll
    for (int reg = 0; reg < 4; ++reg) {
      const int rloc = i * 16 + lq * 4 + reg;
      const float hv = hvv[i][reg];
      hseqS[rloc * 64 + w * 16 + lr] = hv;
      float sv = hv * SC;
      _Float16 hi = (_Float16)sv;
      _Float16 lo = (_Float16)(sv - (float)hi);
      h16S[(kcl * 2 + 0) * 2048 + rloc * 32 + kk] = hi;
      h16S[(kcl * 2 + 1) * 2048 + rloc * 32 + kk] = lo;
      float p = hv * whv;
#pragma unroll
      for (int m = 1; m < 16; m <<= 1) p += __shfl_xor(p, m, 64);
      if (lr == 0) lds_hp[rloc][w] = p;
    }
  __syncthreads();

  // dump h_seq: 64 rows x 256B contiguous segments (16 lanes per segment)
#pragma unroll
  for (int k = 0; k < 4; ++k) {
    int cid = k * 256 + tid;              // 0..1023 16B-chunks
    int row = cid >> 4, ch16 = cid & 15;
    *(float4*)&out[OUT_HSEQ + (long)(rb + row) * (T * H) + (long)t * H + c0 + ch16 * 4] =
        *(const float4*)&hseqS[row * 64 + ch16 * 4];
  }
  // dump h16: one contiguous 16KB block (strip's 2 kc x 2 planes)
  {
    _Float16* dst = h16 + (long)t * H16_PER_T + tilebase + (long)(2 * strip) * 4096;
#pragma unroll
    for (int k = 0; k < 4; ++k) {
      int cid = k * 256 + tid;            // 16B chunks of 16KB
      *(float4*)&dst[cid * 8] = *(const float4*)&h16S[cid * 8];
    }
  }
  if (tid < 64)
    hp4[((long)t * 4 + strip) * B + rb + tid] =
        ((lds_hp[tid][0] + lds_hp[tid][1]) + (lds_hp[tid][2] + lds_hp[tid][3]));
}

// ---------------------------------------------------------------------------
// Readout: [B*T,256] x [256,112] single-product f16 (cols 0..99 kept).
// A = h16 hi-plane via DMA. Block = (t, 128-row b-tile) = two 64-row tiles.
__global__ __launch_bounds__(256, 4) void k_lseq(
    const _Float16* __restrict__ h16, const _Float16* __restrict__ waug,
    const float* __restrict__ b_ro, float* __restrict__ lseq) {
  __shared__ __align__(16) _Float16 As[128 * 32];
  __shared__ __align__(16) _Float16 Bs[112 * 32];
  const int tid = threadIdx.x;
  const int w = tid >> 6, l = tid & 63;
  const int lr = l & 15, lq = l >> 4;
  const int t = blockIdx.x >> 9;
  const int btile = blockIdx.x & 511;
  const _Float16* h16r = h16 + (long)t * H16_PER_T + (long)btile * 65536;

  f4 acc[2][7];
#pragma unroll
  for (int i = 0; i < 2; ++i)
#pragma unroll
    for (int j = 0; j < 7; ++j) acc[i][j] = (f4)0.f;

  for (int kc = 0; kc < 8; ++kc) {
    const int k0 = kc * 32;
    __syncthreads();
    // stage A hi-plane via DMA: 8 x 1KB chunks (2 tiles x 4), 2 per wave
#pragma unroll
    for (int j = 0; j < 2; ++j) {
      int c = w * 2 + j;   // 0..7; c>>2 selects 64-row tile
      gload_lds16(h16r + (long)(c >> 2) * 32768 + (long)kc * 4096 + (c & 3) * 512 + l * 8,
                  &As[c * 512]);
    }
    // stage B hi-plane via async DMA: 7 x 1KB chunks
#pragma unroll
    for (int j = 0; j < 2; ++j) {
      int chunk = w + j * 4;
      if (chunk < 7) {
        int scol = chunk * 16 + (l >> 2);
        int kq = l & 3;
        gload_lds16(waug + (long)scol * H + k0 + kq * 8, &Bs[chunk * 512]);
      }
    }
    __syncthreads();
    h8 Af[2];
#pragma unroll
    for (int i = 0; i < 2; ++i)
      Af[i] = *(const h8*)&As[(w * 32 + i * 16 + lr) * 32 + lq * 8];
#pragma unroll
    for (int j = 0; j < 7; ++j) {
      h8 Bf = *(const h8*)&Bs[(j * 16 + lr) * 32 + lq * 8];
#pragma unroll
      for (int i = 0; i < 2; ++i) acc[i][j] = MFMA16(Af[i], Bf, acc[i][j]);
    }
  }
#pragma unroll
  for (int j = 0; j < 7; ++j) {
    const int col = j * 16 + lr;
    if (col < C) {
      const float br = b_ro[col];
#pragma unroll
      for (int i = 0; i < 2; ++i)
#pragma unroll
        for (int reg = 0; reg < 4; ++reg) {
          long b = (long)btile * 128 + w * 32 + i * 16 + lq * 4 + reg;
          lseq[(b * T + t) * C + col] = fmaf(acc[i][j][reg], SB, br);
        }
    }
  }
}

// ---------------------------------------------------------------------------
// Per-row: halt[t] = sigmoid(b_halt + 4 strip partials), then ACT chain.
__global__ void k_act(const float* __restrict__ hp4, const float* __restrict__ b_halt,
                      float* __restrict__ out, float* __restrict__ swb,
                      float* __restrict__ nupb, float* __restrict__ remb) {
  const long b = (long)blockIdx.x * 256 + threadIdx.x;
  const float bh = b_halt[0];
  float cum = 0.f, rem = 0.f, nu = 0.f;
#pragma unroll
  for (int t = 0; t < T; ++t) {
    float v = bh + hp4[((long)t * 4 + 0) * B + b] + hp4[((long)t * 4 + 1) * B + b] +
              hp4[((long)t * 4 + 2) * B + b] + hp4[((long)t * 4 + 3) * B + b];
    float halt = sigmoidf_(v);
    out[OUT_HALT + b * T + t] = halt;
    float still = (cum < 0.99f) ? 1.f : 0.f;
    float nh = halt * still;
    float would = ((cum + nh) > 0.99f) ? 1.f : 0.f;
    float rema = (1.f - cum) * would * still;
    float swv = nh * (1.f - would) + rema;
    cum += swv; rem += rema; nu += still;
    swb[b * T + t] = swv;
  }
  nupb[b] = nu; remb[b] = rem;
}

// ---------------------------------------------------------------------------
__global__ void k_logits(const float* __restrict__ lseq, const float* __restrict__ swb,
                         const float* __restrict__ b_ro, const float* __restrict__ nupb,
                         float* __restrict__ out) {
  const long b = blockIdx.x;
  const int tid = threadIdx.x;
  if (tid < C) {
    float br = b_ro[tid];
    float s = br;
#pragma unroll
    for (int t = 0; t < T; ++t) {
      float sw = swb[b * T + t];
      s = fmaf(sw, lseq[(b * T + t) * C + tid] - br, s);
    }
    out[OUT_LOGITS + b * C + tid] = s;
  } else if (tid == C) {
    out[OUT_NUP + b] = nupb[b];
  }
}

// ---------------------------------------------------------------------------
__global__ void k_ponder(const float* __restrict__ nupb, const float* __restrict__ remb,
                         float* __restrict__ out) {
  __shared__ float sm[4];
  float s = 0.f;
  for (int i = threadIdx.x; i < B; i += 256) s += nupb[i] + remb[i];
#pragma unroll
  for (int m = 1; m < 64; m <<= 1) s += __shfl_xor(s, m, 64);
  int w = threadIdx.x >> 6;
  if ((threadIdx.x & 63) == 0) sm[w] = s;
  __syncthreads();
  if (threadIdx.x == 0)
    out[OUT_PONDER] = (sm[0] + sm[1] + sm[2] + sm[3]) * (1.f / (float)B);
}

// ---------------------------------------------------------------------------
extern "C" void kernel_launch(void* const* d_in, const int* in_sizes, int n_in,
                              void* d_out, int out_size, void* d_ws, size_t ws_size,
                              hipStream_t stream) {
  const float* x      = (const float*)d_in[0];
  const float* W_ih   = (const float*)d_in[1];
  const float* W_hh   = (const float*)d_in[2];
  const float* b_ih   = (const float*)d_in[3];
  const float* b_hh   = (const float*)d_in[4];
  const float* W_halt = (const float*)d_in[5];
  const float* b_halt = (const float*)d_in[6];
  const float* W_ro   = (const float*)d_in[7];
  const float* b_ro   = (const float*)d_in[8];
  float* out = (float*)d_out;
  float* ws  = (float*)d_ws;

  float* xpt       = ws + WS_XP;
  _Float16* w16    = (_Float16*)(ws + WS_W16);
  _Float16* wih16  = w16;
  _Float16* whh16  = w16 + 2 * NIH;
  _Float16* waug16 = w16 + 2 * (NIH + NHH);
  float* swb  = ws + WS_HL;
  float* hp4  = ws + WS_HP4;
  float* nupb = ws + WS_NUPB;
  float* remb = ws + WS_REMB;
  _Float16* h16 = (_Float16*)(ws + WS_H16);   // per-t pre-split h planes

  k_prep<<<(int)((NIH + 255) / 256), 256, 0, stream>>>(W_ih, W_hh, W_ro, W_halt, w16);
  k_xproj<<<2048, 256, 0, stream>>>(x, wih16, b_ih, b_hh, W_halt, xpt, out, h16, hp4);
  for (int t = 1; t < T; ++t)
    k_gru<<<4096, 256, 0, stream>>>(whh16, xpt, b_hh, W_halt, out, h16, hp4, t);
  k_lseq<<<512 * T, 256, 0, stream>>>(h16, waug16, b_ro, out + OUT_LSEQ);
  k_act<<<B / 256, 256, 0, stream>>>(hp4, b_halt, out, swb, nupb, remb);
  k_logits<<<B, 128, 0, stream>>>(out + OUT_LSEQ, swb, b_ro, nupb, out);
  k_ponder<<<1, 256, 0, stream>>>(nupb, remb, out);
}

// Round 20
// 1982.576 us; speedup vs baseline: 1.2514x; 1.2514x over previous
//
#include <hip/hip_runtime.h>
#include <cmath>

// ---------------------------------------------------------------------------
// ACT classifier (B=65536, D=512, H=256, C=100, T=10).
// Round 20 = round 19 + ONE-TOKEN FIX: '#pragma unroll' on the t=0-fold tl
// loop. r19's counters showed the exact rule-#20 signature: runtime tl in
// acc[tl*4+ii] spilled all 96 accumulator VGPRs to scratch (VGPR_Count=80,
// WRITE 3.67GB phantom traffic, k_xproj 745us). Unrolling makes every acc
// index compile-time. Numerics already proven bit-identical in r19
// (canary 0.0078125 held); this is purely a codegen fix.
// ---------------------------------------------------------------------------

namespace {
constexpr int B = 65536, D = 512, H = 256, C = 100, T = 10;

// output layout (flat float elements, reference return order)
constexpr long OUT_LOGITS = 0;
constexpr long OUT_PONDER = (long)B * C;
constexpr long OUT_NUP    = OUT_PONDER + 1;
constexpr long OUT_HSEQ   = OUT_NUP + B;
constexpr long OUT_HALT   = OUT_HSEQ + (long)B * T * H;
constexpr long OUT_LSEQ   = OUT_HALT + (long)B * T;

// weight plane sizes (elements)
constexpr long NIH  = 768L * D;   // 393216
constexpr long NHH  = 768L * H;   // 196608
constexpr long NAUG = 112L * H;   // 28672

// workspace layout (float units)
constexpr long WS_XP   = 0;                          // xpt [B*768] f32 (tiled)
constexpr long WS_W16  = WS_XP + (long)B * 768;      // f16 planes (2x each W)
constexpr long W_HALV  = 2 * (NIH + NHH + NAUG);
constexpr long WS_HL   = WS_W16 + (W_HALV + 1) / 2;  // step_w [B][T]
constexpr long WS_HP4  = WS_HL + (long)B * T;        // halt partials [T][4][B]
constexpr long WS_NUPB = WS_HP4 + 4L * B * T;
constexpr long WS_REMB = WS_NUPB + B;
constexpr long WS_H16  = WS_REMB + B;                // h16 planes, per t
// h16: [t][tile 1024][kc 8][plane 2][r 64][kk 32] halves
constexpr long H16_PER_T = 1024L * 32768;            // 33,554,432 halves / t

constexpr float SC  = 256.f;           // operand pre-scale 2^8
constexpr float ISC = 1.f / 256.f;     // single-operand scale-back 2^-8
constexpr float SB  = 1.f / 65536.f;   // product scale-back 2^-16 (exact)
} // namespace

typedef __attribute__((ext_vector_type(8))) _Float16 h8;
typedef __attribute__((ext_vector_type(4))) _Float16 h4;
typedef __attribute__((ext_vector_type(4))) float f4;

#define MFMA16(A, Bo, Cc) __builtin_amdgcn_mfma_f32_16x16x32_f16(A, Bo, Cc, 0, 0, 0)
// 3-product 2-split accumulate, smallest first
#define PROD3(a, Ah, Al, Bh, Bl)                                               \
  a = MFMA16(Al, Bh, a);                                                       \
  a = MFMA16(Ah, Bl, a);                                                       \
  a = MFMA16(Ah, Bh, a);

__device__ __forceinline__ float sigmoidf_(float x) {
  if (x >= 0.f) { return 1.f / (1.f + expf(-x)); }
  float e = expf(x);
  return e / (1.f + e);
}

// async global->LDS DMA, 16 B per lane; lds base wave-uniform, fills
// base + lane*16 linearly; global src is per-lane.
__device__ __forceinline__ void gload_lds16(const _Float16* g, _Float16* l) {
  __builtin_amdgcn_global_load_lds(
      (const __attribute__((address_space(1))) unsigned int*)g,
      (__attribute__((address_space(3))) unsigned int*)l, 16, 0, 0);
}

// ---------------------------------------------------------------------------
// split weights (pre-scaled by 2^8) into f16 hi/lo planes
__global__ void k_prep(const float* __restrict__ wih_s, const float* __restrict__ whh_s,
                       const float* __restrict__ wro, const float* __restrict__ whalt,
                       _Float16* __restrict__ wr) {
  long idx = (long)blockIdx.x * 256 + threadIdx.x;
  if (idx < NIH) {
    float xs = wih_s[idx] * SC;
    _Float16 h = (_Float16)xs;
    _Float16 l = (_Float16)(xs - (float)h);
    wr[idx] = h; wr[NIH + idx] = l;
  }
  if (idx < NHH) {
    float xs = whh_s[idx] * SC;
    _Float16 h = (_Float16)xs;
    _Float16 l = (_Float16)(xs - (float)h);
    long b = 2 * NIH;
    wr[b + idx] = h; wr[b + NHH + idx] = l;
  }
  if (idx < NAUG) {
    int row = (int)(idx >> 8), k = (int)(idx & 255);
    float x = (row < C) ? wro[row * 256 + k] : ((row == C) ? whalt[k] : 0.f);
    float xs = x * SC;
    _Float16 h = (_Float16)xs;
    _Float16 l = (_Float16)(xs - (float)h);
    long b = 2 * (NIH + NHH);
    wr[b + idx] = h; wr[b + NAUG + idx] = l;
  }
}

// stage 16 fp32 elems (scaled) as f16 hi/lo into LDS at row*40+kk0
__device__ __forceinline__ void stageA16(const float* __restrict__ src,
                                         _Float16* As0, _Float16* As1,
                                         int o) {
#pragma unroll
  for (int i = 0; i < 4; ++i) {
    float4 v = ((const float4*)src)[i];
    float vv[4] = {v.x, v.y, v.z, v.w};
    h4 hh, ll;
#pragma unroll
    for (int c = 0; c < 4; ++c) {
      float sv = vv[c] * SC;
      _Float16 h = (_Float16)sv;
      hh[c] = h;
      ll[c] = (_Float16)(sv - (float)h);
    }
    *(h4*)&As0[o + i * 4] = hh;
    *(h4*)&As1[o + i * 4] = ll;
  }
}

// ---------------------------------------------------------------------------
// xpt = x @ W_ih^T + b_ih, stored TILED in MFMA C-fragment order; ALSO
// computes the t=0 GRU output (h_seq[0], h16[0], halt partials) from the
// same register values. Grid 2048 (XCD-swizzled: 512 row-tiles x 4 strips).
__global__ __launch_bounds__(256, 3) void k_xproj(
    const float* __restrict__ x, const _Float16* __restrict__ wih,
    const float* __restrict__ b_ih, const float* __restrict__ b_hh,
    const float* __restrict__ w_halt, float* __restrict__ xpt,
    float* __restrict__ out, _Float16* __restrict__ h16,
    float* __restrict__ hp4) {
  __shared__ __align__(16) char uSmem[45056];   // As0|As1|Bs0|Bs1  /  hseqS|h16S
  _Float16* As0 = (_Float16*)uSmem;             // [128*40] 10240 B
  _Float16* As1 = (_Float16*)(uSmem + 10240);   // [128*40] 10240 B
  _Float16* Bs0 = (_Float16*)(uSmem + 20480);   // [192*32] 12288 B
  _Float16* Bs1 = (_Float16*)(uSmem + 32768);   // [192*32] 12288 B
  float*    hseqS = (float*)uSmem;              // [64][64] 16 KB (per pass)
  _Float16* h16S  = (_Float16*)(uSmem + 16384); // [4][64][32] 16 KB (per pass)
  __shared__ float lds_hp[128][4];
  const int tid = threadIdx.x;
  const int w = tid >> 6, l = tid & 63;
  const int lr = l & 15, lq = l >> 4;
  const int bid = blockIdx.x;
  const int gid = (bid & 7) * 256 + (bid >> 3);   // XCD-contiguous
  const int c0 = (gid & 3) * 64;
  const int rb = (gid >> 2) * 128;

  f4 acc[8][3];
#pragma unroll
  for (int i = 0; i < 8; ++i)
#pragma unroll
    for (int g = 0; g < 3; ++g) acc[i][g] = (f4)0.f;

  for (int kc = 0; kc < 16; ++kc) {
    const int k0 = kc * 32;
    __syncthreads();
    {  // stage A (x rows, scaled split)
      const int row = tid >> 1, kk0 = (tid & 1) * 16;
      stageA16(x + (long)(rb + row) * D + k0 + kk0, As0, As1, row * 40 + kk0);
    }
    // stage B via async DMA: 2 planes x 12 KB, 6 x 1KB chunks per wave
#pragma unroll
    for (int j = 0; j < 6; ++j) {
      int chunk = w * 6 + j;           // 0..23
      int plane = chunk / 12;
      int rem = chunk - plane * 12;
      int scol = rem * 16 + (l >> 2);
      int kq = l & 3;
      int gcol = (scol >> 6) * 256 + c0 + (scol & 63);
      gload_lds16(wih + (long)plane * NIH + (long)gcol * D + k0 + kq * 8,
                  (plane ? Bs1 : Bs0) + rem * 512);
    }
    __syncthreads();
    h8 Bh[3], Bl[3];
#pragma unroll
    for (int g = 0; g < 3; ++g) {
      Bh[g] = *(const h8*)&Bs0[(g * 64 + w * 16 + lr) * 32 + lq * 8];
      Bl[g] = *(const h8*)&Bs1[(g * 64 + w * 16 + lr) * 32 + lq * 8];
    }
#pragma unroll
    for (int i = 0; i < 8; ++i) {
      h8 Ah = *(const h8*)&As0[(i * 16 + lr) * 40 + lq * 8];
      h8 Al = *(const h8*)&As1[(i * 16 + lr) * 40 + lq * 8];
#pragma unroll
      for (int g = 0; g < 3; ++g) { PROD3(acc[i][g], Ah, Al, Bh[g], Bl[g]); }
    }
  }
  const int ch = c0 + w * 16 + lr;
  const int strip = gid & 3;
  float bi[3] = {b_ih[ch], b_ih[256 + ch], b_ih[512 + ch]};
  const long xoff = (long)(lq * 256 + w * 64 + lr * 4);
#pragma unroll
  for (int i = 0; i < 8; ++i) {
    const long t4s = (long)((gid >> 2) * 2 + (i >> 2)) * 4 + strip;
#pragma unroll
    for (int g = 0; g < 3; ++g) {
      float4 v = make_float4(fmaf(acc[i][g][0], SB, bi[g]),
                             fmaf(acc[i][g][1], SB, bi[g]),
                             fmaf(acc[i][g][2], SB, bi[g]),
                             fmaf(acc[i][g][3], SB, bi[g]));
      *(float4*)&xpt[((t4s * 3 + g) * 4 + (i & 3)) * 1024 + xoff] = v;
    }
  }

  // ---- t=0 GRU fold: gates on the same register values; two 64-row passes.
  // UNROLLED so all acc indices are compile-time (rule #20: runtime-indexed
  // ext_vector arrays spill to scratch — r19's 745us k_xproj regression).
  const float bhr = b_hh[ch], bhz = b_hh[256 + ch], bhn = b_hh[512 + ch];
  const float whv = w_halt[ch];
  const int kcl = w >> 1;                 // local kc within strip (0/1)
  const int kk = (w & 1) * 16 + lr;       // ch & 31
#pragma unroll
  for (int tl = 0; tl < 2; ++tl) {
    __syncthreads();                      // As/Bs reads done / prev pass done
#pragma unroll
    for (int ii = 0; ii < 4; ++ii) {
      const int i = tl * 4 + ii;
#pragma unroll
      for (int reg = 0; reg < 4; ++reg) {
        const int rloc = ii * 16 + lq * 4 + reg;
        float xrv = fmaf(acc[i][0][reg], SB, bi[0]);
        float xzv = fmaf(acc[i][1][reg], SB, bi[1]);
        float xnv = fmaf(acc[i][2][reg], SB, bi[2]);
        float rr = sigmoidf_(xrv + bhr);
        float zz = sigmoidf_(xzv + bhz);
        float nn = tanhf(xnv + rr * bhn);
        float hv = (1.f - zz) * nn + zz * 0.f;
        hseqS[rloc * 64 + w * 16 + lr] = hv;
        float sv = hv * SC;
        _Float16 hi = (_Float16)sv;
        _Float16 lo = (_Float16)(sv - (float)hi);
        h16S[(kcl * 2 + 0) * 2048 + rloc * 32 + kk] = hi;
        h16S[(kcl * 2 + 1) * 2048 + rloc * 32 + kk] = lo;
        float p = hv * whv;
#pragma unroll
        for (int m = 1; m < 16; m <<= 1) p += __shfl_xor(p, m, 64);
        if (lr == 0) lds_hp[tl * 64 + rloc][w] = p;
      }
    }
    __syncthreads();
    // dump h_seq rows of this tile (t=0), 256B contiguous segments
#pragma unroll
    for (int k = 0; k < 4; ++k) {
      int cid = k * 256 + tid;            // 0..1023 16B-chunks
      int row = cid >> 4, ch16 = cid & 15;
      *(float4*)&out[OUT_HSEQ + (long)(rb + tl * 64 + row) * (T * H) + c0 + ch16 * 4] =
          *(const float4*)&hseqS[row * 64 + ch16 * 4];
    }
    // dump h16[t=0] for tile (rb>>6)+tl: one contiguous 16KB block
    {
      _Float16* dst = h16 + ((long)(rb >> 6) + tl) * 32768 + (long)(2 * strip) * 4096;
#pragma unroll
      for (int k = 0; k < 4; ++k) {
        int cid = k * 256 + tid;          // 16B chunks of 16KB
        *(float4*)&dst[cid * 8] = *(const float4*)&h16S[cid * 8];
      }
    }
  }
  __syncthreads();
  if (tid < 128)
    hp4[(long)strip * B + rb + tid] =
        (lds_hp[tid][0] + lds_hp[tid][1]) + (lds_hp[tid][2] + lds_hp[tid][3]);
}

// ---------------------------------------------------------------------------
// One GRU step, 64-row tiles (round 12 structure; runs t=1..9). Epilogue
// stores staged in LDS (aliasing As/Bs) and dumped as contiguous segments.
__global__ __launch_bounds__(256, 4) void k_gru(
    const _Float16* __restrict__ whh, const float* __restrict__ xpt,
    const float* __restrict__ b_hh, const float* __restrict__ w_halt,
    float* __restrict__ out, _Float16* __restrict__ h16,
    float* __restrict__ hp4, int t) {
  __shared__ __align__(16) char uSmem[32768];      // As(8K)+Bs(24K) | hseqS(16K)+h16S(16K)
  _Float16* As0 = (_Float16*)uSmem;                // [64*32] plane 0
  _Float16* As1 = (_Float16*)(uSmem + 4096);       // [64*32] plane 1
  _Float16* Bs0 = (_Float16*)(uSmem + 8192);       // [192*32] plane 0
  _Float16* Bs1 = (_Float16*)(uSmem + 20480);      // [192*32] plane 1
  float*    hseqS = (float*)uSmem;                 // [64][64] post-loop
  _Float16* h16S  = (_Float16*)(uSmem + 16384);    // [4][64][32] post-loop
  __shared__ float lds_hp[64][4];
  const int tid = threadIdx.x;
  const int w = tid >> 6, l = tid & 63;
  const int lr = l & 15, lq = l >> 4;
  const int bid = blockIdx.x;
  const int gid = (bid & 7) * 512 + (bid >> 3);   // XCD-contiguous
  const int strip = gid & 3;
  const int c0 = strip * 64;
  const int rb = (gid >> 2) * 64;
  const long tilebase = (long)(rb >> 6) * 32768;  // 8 kc * 2 planes * 2048
  const int ch = c0 + w * 16 + lr;
  const int kc_h = ch >> 5;                       // wave-uniform

  f4 acc[4][3];
  float ho[4][4];
  float xnv[4][4];
  // init: coalesced float4 fragment loads; xr/xz folded into acc (exact
  // *2^16), xn prefetched.
  const long t4s = (long)(gid >> 2) * 4 + strip;
  const long xoff = (long)(lq * 256 + w * 64 + lr * 4);
#pragma unroll
  for (int i = 0; i < 4; ++i) {
    float4 vr = *(const float4*)&xpt[((t4s * 3 + 0) * 4 + i) * 1024 + xoff];
    float4 vz = *(const float4*)&xpt[((t4s * 3 + 1) * 4 + i) * 1024 + xoff];
    float4 vn = *(const float4*)&xpt[((t4s * 3 + 2) * 4 + i) * 1024 + xoff];
    acc[i][0][0] = vr.x * 65536.f; acc[i][0][1] = vr.y * 65536.f;
    acc[i][0][2] = vr.z * 65536.f; acc[i][0][3] = vr.w * 65536.f;
    acc[i][1][0] = vz.x * 65536.f; acc[i][1][1] = vz.y * 65536.f;
    acc[i][1][2] = vz.z * 65536.f; acc[i][1][3] = vz.w * 65536.f;
    xnv[i][0] = vn.x; xnv[i][1] = vn.y; xnv[i][2] = vn.z; xnv[i][3] = vn.w;
    acc[i][2] = (f4)0.f;
#pragma unroll
    for (int reg = 0; reg < 4; ++reg) ho[i][reg] = 0.f;
  }

  if (t > 0) {
    const _Float16* h16r = h16 + (long)(t - 1) * H16_PER_T + tilebase;
    for (int kc = 0; kc < 8; ++kc) {
      const int k0 = kc * 32;
      __syncthreads();
      // stage A via DMA: 2 planes x 4KB = 8 chunks of 1KB; 2 per wave
#pragma unroll
      for (int j = 0; j < 2; ++j) {
        int c = w * 2 + j;          // 0..7
        int plane = c >> 2;
        int cc = c & 3;
        gload_lds16(h16r + (long)kc * 4096 + plane * 2048 + cc * 512 + l * 8,
                    (plane ? As1 : As0) + cc * 512);
      }
      // stage B via DMA: 24 x 1KB chunks, 6 per wave
#pragma unroll
      for (int j = 0; j < 6; ++j) {
        int chunk = w * 6 + j;
        int plane = chunk / 12;
        int rem = chunk - plane * 12;
        int scol = rem * 16 + (l >> 2);
        int kq = l & 3;
        int gcol = (scol >> 6) * 256 + c0 + (scol & 63);
        gload_lds16(whh + (long)plane * NHH + (long)gcol * H + k0 + kq * 8,
                    (plane ? Bs1 : Bs0) + rem * 512);
      }
      __syncthreads();
      h8 Bh[3], Bl[3];
#pragma unroll
      for (int g = 0; g < 3; ++g) {
        Bh[g] = *(const h8*)&Bs0[(g * 64 + w * 16 + lr) * 32 + lq * 8];
        Bl[g] = *(const h8*)&Bs1[(g * 64 + w * 16 + lr) * 32 + lq * 8];
      }
#pragma unroll
      for (int i = 0; i < 4; ++i) {
        h8 Ah = *(const h8*)&As0[(i * 16 + lr) * 32 + lq * 8];
        h8 Al = *(const h8*)&As1[(i * 16 + lr) * 32 + lq * 8];
#pragma unroll
        for (int g = 0; g < 3; ++g) { PROD3(acc[i][g], Ah, Al, Bh[g], Bl[g]); }
      }
      // capture ho = h_{t-1}[row, ch] from this kc's As tile: (hi+lo)/SC
      if (kc == kc_h) {
#pragma unroll
        for (int i = 0; i < 4; ++i)
#pragma unroll
          for (int reg = 0; reg < 4; ++reg) {
            int rloc = i * 16 + lq * 4 + reg;
            ho[i][reg] = ((float)As0[rloc * 32 + (ch & 31)] +
                          (float)As1[rloc * 32 + (ch & 31)]) * ISC;
          }
      }
    }
  }

  // epilogue: gates + h_new in registers (no global loads, no stores yet)
  const float bhr = b_hh[ch], bhz = b_hh[256 + ch], bhn = b_hh[512 + ch];
  const float whv = w_halt[ch];
  float hvv[4][4];
#pragma unroll
  for (int i = 0; i < 4; ++i)
#pragma unroll
    for (int reg = 0; reg < 4; ++reg) {
      float rr = sigmoidf_(fmaf(acc[i][0][reg], SB, bhr));
      float zz = sigmoidf_(fmaf(acc[i][1][reg], SB, bhz));
      float nn = tanhf(xnv[i][reg] + rr * fmaf(acc[i][2][reg], SB, bhn));
      hvv[i][reg] = (1.f - zz) * nn + zz * ho[i][reg];
    }

  __syncthreads();   // As/Bs consumption fully done; alias region reusable

  // stage h_seq + h16 planes into LDS; halt partial via shuffle
  const int kcl = w >> 1;                 // local kc within strip (0/1)
  const int kk = (w & 1) * 16 + lr;       // ch & 31
#pragma unroll
  for (int i = 0; i < 4; ++i)
#pragma unroll
    for (int reg = 0; reg < 4; ++reg) {
      const int rloc = i * 16 + lq * 4 + reg;
      const float hv = hvv[i][reg];
      hseqS[rloc * 64 + w * 16 + lr] = hv;
      float sv = hv * SC;
      _Float16 hi = (_Float16)sv;
      _Float16 lo = (_Float16)(sv - (float)hi);
      h16S[(kcl * 2 + 0) * 2048 + rloc * 32 + kk] = hi;
      h16S[(kcl * 2 + 1) * 2048 + rloc * 32 + kk] = lo;
      float p = hv * whv;
#pragma unroll
      for (int m = 1; m < 16; m <<= 1) p += __shfl_xor(p, m, 64);
      if (lr == 0) lds_hp[rloc][w] = p;
    }
  __syncthreads();

  // dump h_seq: 64 rows x 256B contiguous segments (16 lanes per segment)
#pragma unroll
  for (int k = 0; k < 4; ++k) {
    int cid = k * 256 + tid;              // 0..1023 16B-chunks
    int row = cid >> 4, ch16 = cid & 15;
    *(float4*)&out[OUT_HSEQ + (long)(rb + row) * (T * H) + (long)t * H + c0 + ch16 * 4] =
        *(const float4*)&hseqS[row * 64 + ch16 * 4];
  }
  // dump h16: one contiguous 16KB block (strip's 2 kc x 2 planes)
  {
    _Float16* dst = h16 + (long)t * H16_PER_T + tilebase + (long)(2 * strip) * 4096;
#pragma unroll
    for (int k = 0; k < 4; ++k) {
      int cid = k * 256 + tid;            // 16B chunks of 16KB
      *(float4*)&dst[cid * 8] = *(const float4*)&h16S[cid * 8];
    }
  }
  if (tid < 64)
    hp4[((long)t * 4 + strip) * B + rb + tid] =
        ((lds_hp[tid][0] + lds_hp[tid][1]) + (lds_hp[tid][2] + lds_hp[tid][3]));
}

// ---------------------------------------------------------------------------
// Readout: [B*T,256] x [256,112] single-product f16 (cols 0..99 kept).
// A = h16 hi-plane via DMA. Block = (t, 128-row b-tile) = two 64-row tiles.
__global__ __launch_bounds__(256, 4) void k_lseq(
    const _Float16* __restrict__ h16, const _Float16* __restrict__ waug,
    const float* __restrict__ b_ro, float* __restrict__ lseq) {
  __shared__ __align__(16) _Float16 As[128 * 32];
  __shared__ __align__(16) _Float16 Bs[112 * 32];
  const int tid = threadIdx.x;
  const int w = tid >> 6, l = tid & 63;
  const int lr = l & 15, lq = l >> 4;
  const int t = blockIdx.x >> 9;
  const int btile = blockIdx.x & 511;
  const _Float16* h16r = h16 + (long)t * H16_PER_T + (long)btile * 65536;

  f4 acc[2][7];
#pragma unroll
  for (int i = 0; i < 2; ++i)
#pragma unroll
    for (int j = 0; j < 7; ++j) acc[i][j] = (f4)0.f;

  for (int kc = 0; kc < 8; ++kc) {
    const int k0 = kc * 32;
    __syncthreads();
    // stage A hi-plane via DMA: 8 x 1KB chunks (2 tiles x 4), 2 per wave
#pragma unroll
    for (int j = 0; j < 2; ++j) {
      int c = w * 2 + j;   // 0..7; c>>2 selects 64-row tile
      gload_lds16(h16r + (long)(c >> 2) * 32768 + (long)kc * 4096 + (c & 3) * 512 + l * 8,
                  &As[c * 512]);
    }
    // stage B hi-plane via async DMA: 7 x 1KB chunks
#pragma unroll
    for (int j = 0; j < 2; ++j) {
      int chunk = w + j * 4;
      if (chunk < 7) {
        int scol = chunk * 16 + (l >> 2);
        int kq = l & 3;
        gload_lds16(waug + (long)scol * H + k0 + kq * 8, &Bs[chunk * 512]);
      }
    }
    __syncthreads();
    h8 Af[2];
#pragma unroll
    for (int i = 0; i < 2; ++i)
      Af[i] = *(const h8*)&As[(w * 32 + i * 16 + lr) * 32 + lq * 8];
#pragma unroll
    for (int j = 0; j < 7; ++j) {
      h8 Bf = *(const h8*)&Bs[(j * 16 + lr) * 32 + lq * 8];
#pragma unroll
      for (int i = 0; i < 2; ++i) acc[i][j] = MFMA16(Af[i], Bf, acc[i][j]);
    }
  }
#pragma unroll
  for (int j = 0; j < 7; ++j) {
    const int col = j * 16 + lr;
    if (col < C) {
      const float br = b_ro[col];
#pragma unroll
      for (int i = 0; i < 2; ++i)
#pragma unroll
        for (int reg = 0; reg < 4; ++reg) {
          long b = (long)btile * 128 + w * 32 + i * 16 + lq * 4 + reg;
          lseq[(b * T + t) * C + col] = fmaf(acc[i][j][reg], SB, br);
        }
    }
  }
}

// ---------------------------------------------------------------------------
// Per-row: halt[t] = sigmoid(b_halt + 4 strip partials), then ACT chain.
__global__ void k_act(const float* __restrict__ hp4, const float* __restrict__ b_halt,
                      float* __restrict__ out, float* __restrict__ swb,
                      float* __restrict__ nupb, float* __restrict__ remb) {
  const long b = (long)blockIdx.x * 256 + threadIdx.x;
  const float bh = b_halt[0];
  float cum = 0.f, rem = 0.f, nu = 0.f;
#pragma unroll
  for (int t = 0; t < T; ++t) {
    float v = bh + hp4[((long)t * 4 + 0) * B + b] + hp4[((long)t * 4 + 1) * B + b] +
              hp4[((long)t * 4 + 2) * B + b] + hp4[((long)t * 4 + 3) * B + b];
    float halt = sigmoidf_(v);
    out[OUT_HALT + b * T + t] = halt;
    float still = (cum < 0.99f) ? 1.f : 0.f;
    float nh = halt * still;
    float would = ((cum + nh) > 0.99f) ? 1.f : 0.f;
    float rema = (1.f - cum) * would * still;
    float swv = nh * (1.f - would) + rema;
    cum += swv; rem += rema; nu += still;
    swb[b * T + t] = swv;
  }
  nupb[b] = nu; remb[b] = rem;
}

// ---------------------------------------------------------------------------
__global__ void k_logits(const float* __restrict__ lseq, const float* __restrict__ swb,
                         const float* __restrict__ b_ro, const float* __restrict__ nupb,
                         float* __restrict__ out) {
  const long b = blockIdx.x;
  const int tid = threadIdx.x;
  if (tid < C) {
    float br = b_ro[tid];
    float s = br;
#pragma unroll
    for (int t = 0; t < T; ++t) {
      float sw = swb[b * T + t];
      s = fmaf(sw, lseq[(b * T + t) * C + tid] - br, s);
    }
    out[OUT_LOGITS + b * C + tid] = s;
  } else if (tid == C) {
    out[OUT_NUP + b] = nupb[b];
  }
}

// ---------------------------------------------------------------------------
__global__ void k_ponder(const float* __restrict__ nupb, const float* __restrict__ remb,
                         float* __restrict__ out) {
  __shared__ float sm[4];
  float s = 0.f;
  for (int i = threadIdx.x; i < B; i += 256) s += nupb[i] + remb[i];
#pragma unroll
  for (int m = 1; m < 64; m <<= 1) s += __shfl_xor(s, m, 64);
  int w = threadIdx.x >> 6;
  if ((threadIdx.x & 63) == 0) sm[w] = s;
  __syncthreads();
  if (threadIdx.x == 0)
    out[OUT_PONDER] = (sm[0] + sm[1] + sm[2] + sm[3]) * (1.f / (float)B);
}

// ---------------------------------------------------------------------------
extern "C" void kernel_launch(void* const* d_in, const int* in_sizes, int n_in,
                              void* d_out, int out_size, void* d_ws, size_t ws_size,
                              hipStream_t stream) {
  const float* x      = (const float*)d_in[0];
  const float* W_ih   = (const float*)d_in[1];
  const float* W_hh   = (const float*)d_in[2];
  const float* b_ih   = (const float*)d_in[3];
  const float* b_hh   = (const float*)d_in[4];
  const float* W_halt = (const float*)d_in[5];
  const float* b_halt = (const float*)d_in[6];
  const float* W_ro   = (const float*)d_in[7];
  const float* b_ro   = (const float*)d_in[8];
  float* out = (float*)d_out;
  float* ws  = (float*)d_ws;

  float* xpt       = ws + WS_XP;
  _Float16* w16    = (_Float16*)(ws + WS_W16);
  _Float16* wih16  = w16;
  _Float16* whh16  = w16 + 2 * NIH;
  _Float16* waug16 = w16 + 2 * (NIH + NHH);
  float* swb  = ws + WS_HL;
  float* hp4  = ws + WS_HP4;
  float* nupb = ws + WS_NUPB;
  float* remb = ws + WS_REMB;
  _Float16* h16 = (_Float16*)(ws + WS_H16);   // per-t pre-split h planes

  k_prep<<<(int)((NIH + 255) / 256), 256, 0, stream>>>(W_ih, W_hh, W_ro, W_halt, w16);
  k_xproj<<<2048, 256, 0, stream>>>(x, wih16, b_ih, b_hh, W_halt, xpt, out, h16, hp4);
  for (int t = 1; t < T; ++t)
    k_gru<<<4096, 256, 0, stream>>>(whh16, xpt, b_hh, W_halt, out, h16, hp4, t);
  k_lseq<<<512 * T, 256, 0, stream>>>(h16, waug16, b_ro, out + OUT_LSEQ);
  k_act<<<B / 256, 256, 0, stream>>>(hp4, b_halt, out, swb, nupb, remb);
  k_logits<<<B, 128, 0, stream>>>(out + OUT_LSEQ, swb, b_ro, nupb, out);
  k_ponder<<<1, 256, 0, stream>>>(nupb, remb, out);
}